// Round 1
// baseline (328.327 us; speedup 1.0000x reference)
//
#include <hip/hip_runtime.h>
#include <hip/hip_bf16.h>
#include <stdint.h>

typedef __attribute__((ext_vector_type(8))) short short8;
typedef __attribute__((ext_vector_type(4))) float floatx4;

#define S_LEN 2048
#define DH    128
#define BQ    64
#define BKV   64
#define NSTEP (S_LEN / BKV)
#define SCALE 0.08838834764831845f   // 1/sqrt(128)

__device__ __forceinline__ unsigned short f2b(float f) {
    union { float f; unsigned u; } v; v.f = f;
    unsigned r = v.u + 0x7fffu + ((v.u >> 16) & 1u);
    return (unsigned short)(r >> 16);
}

// LDS layout (bytes):
//   KH : 0      .. 16384   : K tile, 64 rows x 128 bf16, row stride 256B, XOR-swizzled
//   VT : 16384  .. 33280   : V^T tile, 128 rows x 66 bf16 (132B rows; +2 pad kills bank conflicts)
//   MS : 33280  .. 37376   : mask tile, 64 x 64 bytes
//   PS : 37376  .. 45568   : P buffer, 4 waves x (16 rows x 128B), XOR-swizzled
#define LDS_BYTES 45568

__global__ __launch_bounds__(256, 2)
void attn_fwd(const float* __restrict__ Q, const float* __restrict__ K,
              const float* __restrict__ V, const int* __restrict__ M,
              float* __restrict__ O)
{
    __shared__ __align__(128) char lds[LDS_BYTES];
    char*           KH = lds;
    char*           VT = lds + 16384;
    unsigned char*  MS = (unsigned char*)(lds + 33280);
    char*           PS = lds + 37376;

    const int tid  = threadIdx.x;
    const int lane = tid & 63;
    const int w    = tid >> 6;     // wave 0..3
    const int c    = lane & 15;    // MFMA col / row-in-fragment index
    const int g    = lane >> 4;    // MFMA 16-lane group 0..3
    const int qt   = blockIdx.x;   // 0..31
    const int b    = blockIdx.y;   // 0..15
    const int q0   = qt * BQ;

    // ---- Q fragments: wave w owns q rows q0 + 16w .. +15. A-frag: lane holds
    // Q[q = c][d = 32*dk + 8*g + e], e=0..7, as bf16.
    short8 qf[4];
    {
        const float* qrow = Q + ((size_t)(b * S_LEN + q0 + w * 16 + c)) * DH;
        #pragma unroll
        for (int dk = 0; dk < 4; ++dk) {
            const float* p = qrow + dk * 32 + g * 8;
            float4 a  = *(const float4*)(p);
            float4 bb = *(const float4*)(p + 4);
            short8 f;
            f[0] = f2b(a.x);  f[1] = f2b(a.y);  f[2] = f2b(a.z);  f[3] = f2b(a.w);
            f[4] = f2b(bb.x); f[5] = f2b(bb.y); f[6] = f2b(bb.z); f[7] = f2b(bb.w);
            qf[dk] = f;
        }
    }

    float m_run[4] = {-1e30f, -1e30f, -1e30f, -1e30f};
    float l_run[4] = {0.f, 0.f, 0.f, 0.f};
    floatx4 accO[8];
    #pragma unroll
    for (int i = 0; i < 8; ++i) accO[i] = (floatx4)(0.f);

    const float* Kb = K + (size_t)b * S_LEN * DH;
    const float* Vb = V + (size_t)b * S_LEN * DH;
    const int*   Mb = M + (size_t)b * S_LEN * S_LEN + (size_t)q0 * S_LEN;

    for (int step = 0; step < NSTEP; ++step) {
        const int kv0 = step * BKV;
        __syncthreads();   // previous tile fully consumed before overwrite

        // ---- stage K (bf16, swizzled) and V (bf16, transposed) into LDS
        #pragma unroll
        for (int i = 0; i < 8; ++i) {
            int idx = i * 256 + tid;        // 0..2047
            int row = idx >> 5;             // kv row 0..63
            int c4  = idx & 31;             // float4 column
            float4 kvec = *(const float4*)(Kb + (size_t)(kv0 + row) * DH + c4 * 4);
            unsigned sw = (unsigned)(c4 * 8) ^ (unsigned)((row & 7) << 4);
            unsigned long long kp =
                  (unsigned long long)f2b(kvec.x)
                | ((unsigned long long)f2b(kvec.y) << 16)
                | ((unsigned long long)f2b(kvec.z) << 32)
                | ((unsigned long long)f2b(kvec.w) << 48);
            *(unsigned long long*)(KH + row * 256 + sw) = kp;

            float4 vvec = *(const float4*)(Vb + (size_t)(kv0 + row) * DH + c4 * 4);
            unsigned short vb0[4] = {f2b(vvec.x), f2b(vvec.y), f2b(vvec.z), f2b(vvec.w)};
            #pragma unroll
            for (int j = 0; j < 4; ++j)
                *(unsigned short*)(VT + (c4 * 4 + j) * 132 + row * 2) = vb0[j];
        }
        // ---- stage mask tile as bytes (int32 input, nonzero = masked)
        #pragma unroll
        for (int ii = 0; ii < 4; ++ii) {
            int flat = ii * 1024 + tid * 4;   // 0..4095 over 64x64 tile
            int row  = flat >> 6;
            int col  = flat & 63;
            int4 mi = *(const int4*)(Mb + (size_t)row * S_LEN + kv0 + col);
            uchar4 mb;
            mb.x = mi.x ? 1 : 0; mb.y = mi.y ? 1 : 0;
            mb.z = mi.z ? 1 : 0; mb.w = mi.w ? 1 : 0;
            *(uchar4*)(MS + row * 64 + col) = mb;
        }
        __syncthreads();

        // ---- QK^T: accS[n] rows q=4g+r, col kv = 16n + c
        floatx4 accS[4];
        #pragma unroll
        for (int n = 0; n < 4; ++n) accS[n] = (floatx4)(0.f);
        #pragma unroll
        for (int n = 0; n < 4; ++n) {
            int row = n * 16 + c;   // kv row in tile
            #pragma unroll
            for (int dk = 0; dk < 4; ++dk) {
                unsigned colb = (unsigned)(dk * 64 + g * 16) ^ (unsigned)((row & 7) << 4);
                short8 kf = *(const short8*)(KH + row * 256 + colb);
                accS[n] = __builtin_amdgcn_mfma_f32_16x16x32_bf16(qf[dk], kf, accS[n], 0, 0, 0);
            }
        }

        // ---- online softmax (fp32). Lane's rows: q_local = 4g + r.
        float p[4][4];
        float corr[4];
        #pragma unroll
        for (int r = 0; r < 4; ++r) {
            int qrow = w * 16 + 4 * g + r;   // block-local q row
            float sv[4];
            #pragma unroll
            for (int n = 0; n < 4; ++n) {
                float s = accS[n][r] * SCALE;
                if (MS[qrow * 64 + n * 16 + c]) s = -1e30f;
                sv[n] = s;
            }
            float tm = fmaxf(fmaxf(sv[0], sv[1]), fmaxf(sv[2], sv[3]));
            #pragma unroll
            for (int off = 1; off < 16; off <<= 1)
                tm = fmaxf(tm, __shfl_xor(tm, off, 64));
            float mn = fmaxf(m_run[r], tm);
            corr[r]  = __expf(m_run[r] - mn);
            m_run[r] = mn;
            float ts = 0.f;
            #pragma unroll
            for (int n = 0; n < 4; ++n) { p[n][r] = __expf(sv[n] - mn); ts += p[n][r]; }
            #pragma unroll
            for (int off = 1; off < 16; off <<= 1)
                ts += __shfl_xor(ts, off, 64);
            l_run[r] = l_run[r] * corr[r] + ts;
        }
        #pragma unroll
        for (int s8 = 0; s8 < 8; ++s8) {
            floatx4 o = accO[s8];
            o[0] *= corr[0]; o[1] *= corr[1]; o[2] *= corr[2]; o[3] *= corr[3];
            accO[s8] = o;
        }

        // ---- P -> per-wave LDS (swizzled), then read back as A-fragments.
        // Same-wave produce/consume: no block barrier needed.
        char* psw = PS + w * 2048;
        #pragma unroll
        for (int r = 0; r < 4; ++r) {
            int rl = 4 * g + r;
            #pragma unroll
            for (int n = 0; n < 4; ++n) {
                unsigned colb = (unsigned)((n * 16 + c) * 2) ^ (unsigned)((rl & 7) << 4);
                *(unsigned short*)(psw + rl * 128 + colb) = f2b(p[n][r]);
            }
        }

        // ---- PV: O[q][d] += P(16x64) * V(64x128)
        #pragma unroll
        for (int sub = 0; sub < 2; ++sub) {
            unsigned colb = (unsigned)(sub * 64 + g * 16) ^ (unsigned)((c & 7) << 4);
            short8 pf = *(const short8*)(psw + c * 128 + colb);
            #pragma unroll
            for (int s8 = 0; s8 < 8; ++s8) {
                int d = s8 * 16 + c;
                const int* vip = (const int*)(VT + d * 132 + sub * 64 + g * 16);
                union { int i[4]; short8 v; } u;
                u.i[0] = vip[0]; u.i[1] = vip[1]; u.i[2] = vip[2]; u.i[3] = vip[3];
                accO[s8] = __builtin_amdgcn_mfma_f32_16x16x32_bf16(pf, u.v, accO[s8], 0, 0, 0);
            }
        }
    }

    // ---- epilogue: normalize and store
    float inv[4];
    #pragma unroll
    for (int r = 0; r < 4; ++r) inv[r] = (l_run[r] > 0.f) ? 1.f / l_run[r] : 0.f;
    float* Ob = O + ((size_t)(b * S_LEN + q0 + w * 16)) * DH;
    #pragma unroll
    for (int s8 = 0; s8 < 8; ++s8) {
        #pragma unroll
        for (int r = 0; r < 4; ++r) {
            Ob[(size_t)(4 * g + r) * DH + s8 * 16 + c] = accO[s8][r] * inv[r];
        }
    }
}

extern "C" void kernel_launch(void* const* d_in, const int* in_sizes, int n_in,
                              void* d_out, int out_size, void* d_ws, size_t ws_size,
                              hipStream_t stream) {
    const float* Q = (const float*)d_in[0];
    const float* K = (const float*)d_in[1];
    const float* V = (const float*)d_in[2];
    const int*   M = (const int*)d_in[3];
    float*       O = (float*)d_out;
    dim3 grid(S_LEN / BQ, 16);
    attn_fwd<<<grid, dim3(256), 0, stream>>>(Q, K, V, M, O);
}

// Round 3
// 131.725 us; speedup vs baseline: 2.4925x; 2.4925x over previous
//
#include <hip/hip_runtime.h>
#include <hip/hip_bf16.h>
#include <stdint.h>

typedef __attribute__((ext_vector_type(8))) short short8;
typedef __attribute__((ext_vector_type(4))) float floatx4;

#define S_LEN 2048
#define DH    128
#define BQ    64
#define BKV   64
#define NSTEP (S_LEN / BKV)
#define SCALE 0.08838834764831845f   // 1/sqrt(128)

__device__ __forceinline__ unsigned short f2b(float f) {
    union { float f; unsigned u; } v; v.f = f;
    unsigned r = v.u + 0x7fffu + ((v.u >> 16) & 1u);
    return (unsigned short)(r >> 16);
}

// LDS layout (bytes):
//   KH0 : 0      .. 16384  : K tile buf0, 64 x 256B rows, XOR-swizzled
//   KH1 : 16384  .. 32768  : K tile buf1
//   VT0 : 32768  .. 51200  : V^T buf0, 128 rows x 144B (72 bf16; 16B-aligned rows)
//   VT1 : 51200  .. 69632  : V^T buf1
//   PS  : 69632  .. 77824  : P buffer, 4 waves x 2KB, XOR-swizzled
#define LDS_BYTES 77824

__global__ __launch_bounds__(256, 2)
void attn_fwd(const float* __restrict__ Q, const float* __restrict__ K,
              const float* __restrict__ V, const int* __restrict__ M,
              float* __restrict__ O)
{
    __shared__ __align__(128) char lds[LDS_BYTES];

    const int tid  = threadIdx.x;
    const int lane = tid & 63;
    const int w    = tid >> 6;     // wave 0..3
    const int c    = lane & 15;
    const int g    = lane >> 4;
    const int qt   = blockIdx.x;
    const int b    = blockIdx.y;
    const int q0   = qt * BQ;

    // staging coords
    const int rbase = tid >> 5;          // K row base 0..7 (rows rbase + 8i)
    const int c4    = tid & 31;          // K float4 column
    const unsigned swk = (unsigned)(c4 * 8) ^ (unsigned)(rbase << 4);
    const int vd    = tid & 127;         // V column owned by this thread
    const int vk0   = (tid >> 7) * 32;   // V k-range base (0 or 32)

    // ---- Q fragments (scale folded in): lane holds Q[q=c][d=32*dk+8*g+e]
    short8 qf[4];
    {
        const float* qrow = Q + ((size_t)(b * S_LEN + q0 + w * 16 + c)) * DH;
        #pragma unroll
        for (int dk = 0; dk < 4; ++dk) {
            const float* p = qrow + dk * 32 + g * 8;
            float4 a  = *(const float4*)(p);
            float4 bb = *(const float4*)(p + 4);
            short8 f;
            f[0] = f2b(a.x * SCALE);  f[1] = f2b(a.y * SCALE);
            f[2] = f2b(a.z * SCALE);  f[3] = f2b(a.w * SCALE);
            f[4] = f2b(bb.x * SCALE); f[5] = f2b(bb.y * SCALE);
            f[6] = f2b(bb.z * SCALE); f[7] = f2b(bb.w * SCALE);
            qf[dk] = f;
        }
    }

    float m_run[4] = {-1e30f, -1e30f, -1e30f, -1e30f};
    float l_run[4] = {0.f, 0.f, 0.f, 0.f};
    floatx4 accO[8];
    #pragma unroll
    for (int i = 0; i < 8; ++i) accO[i] = (floatx4)(0.f);

    const float* Kb = K + (size_t)b * S_LEN * DH;
    const float* Vb = V + (size_t)b * S_LEN * DH;
    const int*   Mb = M + (size_t)b * S_LEN * S_LEN + (size_t)q0 * S_LEN;

    // mask row offsets for this thread's 4 q-rows
    size_t moff[4];
    #pragma unroll
    for (int r = 0; r < 4; ++r)
        moff[r] = (size_t)(w * 16 + 4 * g + r) * S_LEN;

    // prefetch registers
    float4 kreg[8];
    float  vreg[32];
    int    mreg[16];

    // ---- prologue: tile 0 loads
    #pragma unroll
    for (int i = 0; i < 8; ++i)
        kreg[i] = *(const float4*)(Kb + (size_t)(i * 8 + rbase) * DH + c4 * 4);
    #pragma unroll
    for (int j = 0; j < 32; ++j)
        vreg[j] = Vb[(size_t)(vk0 + j) * DH + vd];
    #pragma unroll
    for (int r = 0; r < 4; ++r)
        #pragma unroll
        for (int n = 0; n < 4; ++n)
            mreg[r * 4 + n] = Mb[moff[r] + n * 16 + c];

    // write buf0
    #pragma unroll
    for (int i = 0; i < 8; ++i) {
        float4 kv = kreg[i];
        unsigned long long kp =
              (unsigned long long)f2b(kv.x)
            | ((unsigned long long)f2b(kv.y) << 16)
            | ((unsigned long long)f2b(kv.z) << 32)
            | ((unsigned long long)f2b(kv.w) << 48);
        *(unsigned long long*)(lds + (i * 8 + rbase) * 256 + swk) = kp;
    }
    {
        char* vbase = lds + 32768 + vd * 144 + vk0 * 2;
        #pragma unroll
        for (int i = 0; i < 4; ++i) {
            short8 pk;
            #pragma unroll
            for (int e = 0; e < 8; ++e) pk[e] = f2b(vreg[i * 8 + e]);
            *(short8*)(vbase + i * 16) = pk;
        }
    }
    // issue tile-1 K/V loads (consumed at bottom of step 0)
    #pragma unroll
    for (int i = 0; i < 8; ++i)
        kreg[i] = *(const float4*)(Kb + (size_t)(BKV + i * 8 + rbase) * DH + c4 * 4);
    #pragma unroll
    for (int j = 0; j < 32; ++j)
        vreg[j] = Vb[(size_t)(BKV + vk0 + j) * DH + vd];

    __syncthreads();

    char* psw = lds + 69632 + w * 2048;

    for (int step = 0; step < NSTEP; ++step) {
        const int p = step & 1;
        const int kv0 = step * BKV;
        char* KHp = lds + p * 16384;
        char* VTp = lds + 32768 + p * 18432;

        // ---- QK^T from KH[p]
        floatx4 accS[4];
        #pragma unroll
        for (int n = 0; n < 4; ++n) accS[n] = (floatx4)(0.f);
        #pragma unroll
        for (int n = 0; n < 4; ++n) {
            const char* krow = KHp + (n * 16 + c) * 256;
            #pragma unroll
            for (int dk = 0; dk < 4; ++dk) {
                unsigned colb = (unsigned)(dk * 64 + g * 16) ^ (unsigned)((c & 7) << 4);
                short8 kf = *(const short8*)(krow + colb);
                accS[n] = __builtin_amdgcn_mfma_f32_16x16x32_bf16(qf[dk], kf, accS[n], 0, 0, 0);
            }
        }

        // ---- online softmax (mask from regs; scale already folded into Q)
        float pv[4][4];
        float corr[4];
        #pragma unroll
        for (int r = 0; r < 4; ++r) {
            float sv[4];
            #pragma unroll
            for (int n = 0; n < 4; ++n) {
                float s = accS[n][r];
                if (mreg[r * 4 + n]) s = -1e30f;
                sv[n] = s;
            }
            float tm = fmaxf(fmaxf(sv[0], sv[1]), fmaxf(sv[2], sv[3]));
            #pragma unroll
            for (int off = 1; off < 16; off <<= 1)
                tm = fmaxf(tm, __shfl_xor(tm, off, 64));
            float mn = fmaxf(m_run[r], tm);
            corr[r]  = __expf(m_run[r] - mn);
            m_run[r] = mn;
            float ts = 0.f;
            #pragma unroll
            for (int n = 0; n < 4; ++n) { pv[n][r] = __expf(sv[n] - mn); ts += pv[n][r]; }
            #pragma unroll
            for (int off = 1; off < 16; off <<= 1)
                ts += __shfl_xor(ts, off, 64);
            l_run[r] = l_run[r] * corr[r] + ts;
        }
        // issue next-tile mask loads (consumed in next step's softmax)
        if (step + 1 < NSTEP) {
            const int kvn = kv0 + BKV;
            #pragma unroll
            for (int r = 0; r < 4; ++r)
                #pragma unroll
                for (int n = 0; n < 4; ++n)
                    mreg[r * 4 + n] = Mb[moff[r] + kvn + n * 16 + c];
        }

        #pragma unroll
        for (int s8 = 0; s8 < 8; ++s8) {
            floatx4 o = accO[s8];
            o[0] *= corr[0]; o[1] *= corr[1]; o[2] *= corr[2]; o[3] *= corr[3];
            accO[s8] = o;
        }

        // ---- P -> per-wave LDS (swizzled), same-wave consume
        #pragma unroll
        for (int r = 0; r < 4; ++r) {
            int rl = 4 * g + r;
            #pragma unroll
            for (int n = 0; n < 4; ++n) {
                unsigned colb = (unsigned)((n * 16 + c) * 2) ^ (unsigned)((rl & 7) << 4);
                *(unsigned short*)(psw + rl * 128 + colb) = f2b(pv[n][r]);
            }
        }

        // ---- PV from VT[p]
        #pragma unroll
        for (int sub = 0; sub < 2; ++sub) {
            unsigned colb = (unsigned)(sub * 64 + g * 16) ^ (unsigned)((c & 7) << 4);
            short8 pf = *(const short8*)(psw + c * 128 + colb);
            #pragma unroll
            for (int s8 = 0; s8 < 8; ++s8) {
                short8 vf = *(const short8*)(VTp + (s8 * 16 + c) * 144 + sub * 64 + g * 16);
                accO[s8] = __builtin_amdgcn_mfma_f32_16x16x32_bf16(pf, vf, accO[s8], 0, 0, 0);
            }
        }

        // ---- write next tile to LDS buf p^1, then issue tile step+2 loads
        if (step + 1 < NSTEP) {
            char* KHn = lds + (p ^ 1) * 16384;
            char* VTn = lds + 32768 + (p ^ 1) * 18432;
            #pragma unroll
            for (int i = 0; i < 8; ++i) {
                float4 kv = kreg[i];
                unsigned long long kp =
                      (unsigned long long)f2b(kv.x)
                    | ((unsigned long long)f2b(kv.y) << 16)
                    | ((unsigned long long)f2b(kv.z) << 32)
                    | ((unsigned long long)f2b(kv.w) << 48);
                *(unsigned long long*)(KHn + (i * 8 + rbase) * 256 + swk) = kp;
            }
            char* vbase = VTn + vd * 144 + vk0 * 2;
            #pragma unroll
            for (int i = 0; i < 4; ++i) {
                short8 pk;
                #pragma unroll
                for (int e = 0; e < 8; ++e) pk[e] = f2b(vreg[i * 8 + e]);
                *(short8*)(vbase + i * 16) = pk;
            }
            if (step + 2 < NSTEP) {
                const int kvn2 = kv0 + 2 * BKV;
                #pragma unroll
                for (int i = 0; i < 8; ++i)
                    kreg[i] = *(const float4*)(Kb + (size_t)(kvn2 + i * 8 + rbase) * DH + c4 * 4);
                #pragma unroll
                for (int j = 0; j < 32; ++j)
                    vreg[j] = Vb[(size_t)(kvn2 + vk0 + j) * DH + vd];
            }
        }
        __syncthreads();
    }

    // ---- epilogue
    float inv[4];
    #pragma unroll
    for (int r = 0; r < 4; ++r) inv[r] = (l_run[r] > 0.f) ? 1.f / l_run[r] : 0.f;
    float* Ob = O + ((size_t)(b * S_LEN + q0 + w * 16)) * DH;
    #pragma unroll
    for (int s8 = 0; s8 < 8; ++s8) {
        #pragma unroll
        for (int r = 0; r < 4; ++r) {
            Ob[(size_t)(4 * g + r) * DH + s8 * 16 + c] = accO[s8][r] * inv[r];
        }
    }
}

extern "C" void kernel_launch(void* const* d_in, const int* in_sizes, int n_in,
                              void* d_out, int out_size, void* d_ws, size_t ws_size,
                              hipStream_t stream) {
    const float* Q = (const float*)d_in[0];
    const float* K = (const float*)d_in[1];
    const float* V = (const float*)d_in[2];
    const int*   M = (const int*)d_in[3];
    float*       O = (float*)d_out;
    dim3 grid(S_LEN / BQ, 16);
    attn_fwd<<<grid, dim3(256), 0, stream>>>(Q, K, V, M, O);
}